// Round 3
// baseline (638.255 us; speedup 1.0000x reference)
//
#include <hip/hip_runtime.h>

#define B_ 4
#define S_ 2048
#define E_ 512
#define H_ 8
#define D_ 64
#define DFF_ 2048
#define M_ (B_*S_)

typedef unsigned short ushort_t;
typedef __bf16 bf16x8 __attribute__((ext_vector_type(8)));
typedef unsigned short u16x8 __attribute__((ext_vector_type(8)));
typedef float f32x4 __attribute__((ext_vector_type(4)));

__device__ __forceinline__ unsigned short f2bf(float f){
  unsigned int u = __builtin_bit_cast(unsigned int, f);
  unsigned int r = (u + 0x7fffu + ((u >> 16) & 1u)) >> 16;
  return (unsigned short)r;
}
__device__ __forceinline__ float bf2f(unsigned short h){
  unsigned int u = ((unsigned int)h) << 16;
  return __builtin_bit_cast(float, u);
}

#define GLD_LDS16(g, l) __builtin_amdgcn_global_load_lds( \
    (const __attribute__((address_space(1))) void*)(g),   \
    (__attribute__((address_space(3))) void*)(l), 16, 0, 0)

#define MFMA16(a, b, c) __builtin_amdgcn_mfma_f32_16x16x32_bf16((a), (b), (c), 0, 0, 0)

// ---------------- prep kernels ----------------

__global__ __launch_bounds__(256)
void k_cast_x(const float* __restrict__ x, ushort_t* __restrict__ xb){
  const size_t i = ((size_t)blockIdx.x * 256 + threadIdx.x) * 8;
  float4 a = *(const float4*)(x + i);
  float4 c = *(const float4*)(x + i + 4);
  float y[8] = {a.x,a.y,a.z,a.w,c.x,c.y,c.z,c.w};
  u16x8 o;
  #pragma unroll
  for (int j = 0; j < 8; ++j) o[j] = f2bf(y[j]);
  *(u16x8*)(xb + i) = o;
}

// dst[n*K + k] = bf16(src[k*N + n])
__global__ __launch_bounds__(256)
void k_transpose(const float* __restrict__ src, ushort_t* __restrict__ dst, int K, int N){
  __shared__ float t[32][33];
  const int nbn = N >> 5;
  const int bk = blockIdx.x / nbn, bn = blockIdx.x - bk * nbn;
  const int tx = threadIdx.x & 31, ty = threadIdx.x >> 5;
  #pragma unroll
  for (int p = 0; p < 4; ++p)
    t[ty + p*8][tx] = src[(size_t)(bk*32 + ty + p*8) * N + bn*32 + tx];
  __syncthreads();
  #pragma unroll
  for (int p = 0; p < 4; ++p)
    dst[(size_t)(bn*32 + ty + p*8) * K + bk*32 + tx] = f2bf(t[tx][ty + p*8]);
}

__global__ __launch_bounds__(256)
void k_bias3(const float* __restrict__ a, const float* __restrict__ b,
             const float* __restrict__ c, float* __restrict__ o){
  int i = blockIdx.x * 256 + threadIdx.x;
  if (i < 512) o[i] = a[i];
  else if (i < 1024) o[i] = b[i - 512];
  else if (i < 1536) o[i] = c[i - 1024];
}

// ---------------- GEMM: C[M,N] = A[M,K](bf16) @ Bt[N,K](bf16)^T ----------------
// MODE 0: scatter to q/k/v [B,H,S,D] bf16 (+bias)
// MODE 1: f32 out = acc + bias + resid       (resid stride = Nd)
// MODE 2: bf16 out = relu(acc + bias)

template<int MODE>
__global__ __launch_bounds__(256)
void gemm_bt(const ushort_t* __restrict__ A, const ushort_t* __restrict__ Bt,
             const float* __restrict__ bias, const float* __restrict__ resid,
             void* __restrict__ out, int Md, int Nd, int Kd)
{
  __shared__ ushort_t sm[2][2][128*32];
  const int tid = threadIdx.x;
  const int lane = tid & 63, wid = tid >> 6;
  const int wr = wid >> 1, wc = wid & 1;
  const int nbn = Nd >> 7;
  const int bm = blockIdx.x / nbn;
  const int bn = blockIdx.x - bm * nbn;
  const int rq = lane & 15, kg = (lane >> 4) << 3;

  f32x4 acc[4][4];
  #pragma unroll
  for (int i = 0; i < 4; ++i)
    #pragma unroll
    for (int j = 0; j < 4; ++j) acc[i][j] = (f32x4){0.f,0.f,0.f,0.f};

  const int nkt = Kd >> 5;
  const int c0 = tid, c1 = tid + 256;
  const int rA0 = c0 >> 2, koA0 = (c0 & 3) << 3;
  const int rA1 = c1 >> 2, koA1 = (c1 & 3) << 3;
  const ushort_t* Abase = A + (size_t)(bm * 128) * Kd;
  const ushort_t* Bbase = Bt + (size_t)(bn * 128) * Kd;

  auto stage = [&](int buf, int kt){
    const int k0 = kt << 5;
    GLD_LDS16(Abase + (size_t)rA0 * Kd + k0 + koA0, &sm[buf][0][c0 * 8]);
    GLD_LDS16(Abase + (size_t)rA1 * Kd + k0 + koA1, &sm[buf][0][c1 * 8]);
    GLD_LDS16(Bbase + (size_t)rA0 * Kd + k0 + koA0, &sm[buf][1][c0 * 8]);
    GLD_LDS16(Bbase + (size_t)rA1 * Kd + k0 + koA1, &sm[buf][1][c1 * 8]);
  };

  stage(0, 0);
  __syncthreads();
  int cur = 0;
  for (int kt = 0; kt < nkt; ++kt){
    if (kt + 1 < nkt) stage(cur ^ 1, kt + 1);
    const ushort_t* As = &sm[cur][0][0];
    const ushort_t* Bs = &sm[cur][1][0];
    bf16x8 af[4], bfr[4];
    #pragma unroll
    for (int i = 0; i < 4; ++i) af[i]  = *(const bf16x8*)&As[(wr*64 + i*16 + rq)*32 + kg];
    #pragma unroll
    for (int j = 0; j < 4; ++j) bfr[j] = *(const bf16x8*)&Bs[(wc*64 + j*16 + rq)*32 + kg];
    #pragma unroll
    for (int i = 0; i < 4; ++i)
      #pragma unroll
      for (int j = 0; j < 4; ++j)
        acc[i][j] = MFMA16(af[i], bfr[j], acc[i][j]);
    __syncthreads();
    cur ^= 1;
  }

  const int rb = (lane >> 4) << 2;
  #pragma unroll
  for (int i = 0; i < 4; ++i){
    #pragma unroll
    for (int j = 0; j < 4; ++j){
      const int col = bn*128 + wc*64 + j*16 + rq;
      const float bs = bias[col];
      #pragma unroll
      for (int r = 0; r < 4; ++r){
        const int row = bm*128 + wr*64 + i*16 + rb + r;
        const float v = acc[i][j][r] + bs;
        if (MODE == 0){
          ushort_t* o = (ushort_t*)out;
          const int which = col >> 9, hd = col & 511;
          const int hh = hd >> 6, dd = hd & 63;
          const int bb = row >> 11, ss = row & 2047;
          o[(size_t)which*(B_*H_*S_*D_) + (((size_t)(bb*H_ + hh))*S_ + ss)*D_ + dd] = f2bf(v);
        } else if (MODE == 1){
          float* o = (float*)out;
          o[(size_t)row*Nd + col] = v + resid[(size_t)row*Nd + col];
        } else {
          ushort_t* o = (ushort_t*)out;
          o[(size_t)row*Nd + col] = f2bf(fmaxf(v, 0.f));
        }
      }
    }
  }
}

// ---------------- fused flash attention ----------------
// qkv: q,k,v each [B,H,S,D] bf16. out: attnb [B,S,E] bf16.

__global__ __launch_bounds__(256)
void attn_fused(const ushort_t* __restrict__ qkv,
                const float* __restrict__ dist,
                const int* __restrict__ mask,
                ushort_t* __restrict__ attnb)
{
  __shared__ ushort_t Ks[2][64*64];
  __shared__ ushort_t Vts[2][64*64];
  __shared__ ushort_t Ps[4][16*64];

  const int tid = threadIdx.x, lane = tid & 63, w = tid >> 6;
  const int blk = blockIdx.x;
  const int h = blk & 7, qt = (blk >> 3) & 31, b = blk >> 8;
  const size_t plane = (size_t)S_ * D_;
  const ushort_t* Q  = qkv + (size_t)(b*H_ + h) * plane;
  const ushort_t* Kg = Q + (size_t)B_*H_*plane;
  const ushort_t* Vg = Q + 2 * (size_t)B_*H_*plane;

  const int rq = lane & 15, kg = (lane >> 4) << 3;
  const int q0 = qt*64 + w*16;

  bf16x8 qf[2];
  #pragma unroll
  for (int kk = 0; kk < 2; ++kk)
    qf[kk] = *(const bf16x8*)&Q[(size_t)(q0 + rq)*D_ + kk*32 + kg];

  f32x4 ao[4];
  #pragma unroll
  for (int j = 0; j < 4; ++j) ao[j] = (f32x4){0.f,0.f,0.f,0.f};
  float mi[4], li[4];
  #pragma unroll
  for (int r = 0; r < 4; ++r){ mi[r] = -1e30f; li[r] = 0.f; }

  const int cK0 = tid, cK1 = tid + 256;
  auto stageK = [&](int buf, int kt){
    const char* Kt = (const char*)(Kg + (size_t)kt * 64 * D_);
    const int pb0 = cK0 * 16, pb1 = cK1 * 16;
    const int lb0 = pb0 ^ ((((unsigned)pb0 >> 7) & 7) << 4);
    const int lb1 = pb1 ^ ((((unsigned)pb1 >> 7) & 7) << 4);
    GLD_LDS16(Kt + lb0, (char*)&Ks[buf][0] + pb0);
    GLD_LDS16(Kt + lb1, (char*)&Ks[buf][0] + pb1);
  };
  auto loadV = [&](int kt, u16x8* vr){
    const ushort_t* Vt = Vg + (size_t)kt * 64 * D_;
    vr[0] = *(const u16x8*)&Vt[cK0 * 8];
    vr[1] = *(const u16x8*)&Vt[cK1 * 8];
  };
  auto writeV = [&](int buf, const u16x8* vr){
    #pragma unroll
    for (int hh = 0; hh < 2; ++hh){
      const int c = tid + hh * 256;
      const int key = c >> 3, d0 = (c & 7) << 3;
      #pragma unroll
      for (int i2 = 0; i2 < 8; ++i2){
        const int dd = d0 + i2;
        const int lb = dd * 128 + key * 2;
        const int pb = lb ^ ((dd & 7) << 4);
        *(ushort_t*)((char*)&Vts[buf][0] + pb) = vr[hh][i2];
      }
    }
  };

  u16x8 vr0[2];
  stageK(0, 0);
  loadV(0, vr0);
  writeV(0, vr0);
  __syncthreads();

  const float* distq = dist + (size_t)b * S_ * S_;
  const int* maskb = mask + b * S_;
  const int rb = (lane >> 4) << 2;
  const float LOG2E = 1.4426950408889634f;

  int cur = 0;
  const int NT = S_ / 64;
  for (int kt = 0; kt < NT; ++kt){
    u16x8 vn[2];
    if (kt + 1 < NT){
      loadV(kt + 1, vn);
      stageK(cur ^ 1, kt + 1);
    }
    // QK^T
    f32x4 sc[4];
    #pragma unroll
    for (int j = 0; j < 4; ++j) sc[j] = (f32x4){0.f,0.f,0.f,0.f};
    #pragma unroll
    for (int kk = 0; kk < 2; ++kk){
      #pragma unroll
      for (int j = 0; j < 4; ++j){
        const int key = j*16 + rq;
        const int lb = key*128 + (kk*32 + kg)*2;
        const int pb = lb ^ ((key & 7) << 4);
        bf16x8 kf = *(const bf16x8*)((const char*)&Ks[cur][0] + pb);
        sc[j] = MFMA16(qf[kk], kf, sc[j]);
      }
    }
    // scale + dist bias + mask
    float sv[4][4];
    #pragma unroll
    for (int j = 0; j < 4; ++j){
      const int keyg = kt*64 + j*16 + rq;
      const int mk = maskb[keyg];
      #pragma unroll
      for (int r = 0; r < 4; ++r){
        const int qrow = q0 + rb + r;
        float v = sc[j][r] * 0.125f + 0.4f * distq[(size_t)qrow * S_ + keyg];
        sv[j][r] = mk ? v : -1e9f;
      }
    }
    // online softmax (rows live in 16-lane groups)
    float cm[4];
    #pragma unroll
    for (int r = 0; r < 4; ++r)
      cm[r] = fmaxf(fmaxf(sv[0][r], sv[1][r]), fmaxf(sv[2][r], sv[3][r]));
    #pragma unroll
    for (int msk = 1; msk < 16; msk <<= 1)
      #pragma unroll
      for (int r = 0; r < 4; ++r)
        cm[r] = fmaxf(cm[r], __shfl_xor(cm[r], msk));
    float corr[4], rs[4];
    #pragma unroll
    for (int r = 0; r < 4; ++r){
      const float mn = fmaxf(mi[r], cm[r]);
      corr[r] = exp2f((mi[r] - mn) * LOG2E);
      mi[r] = mn; rs[r] = 0.f;
    }
    ushort_t pb16[4][4];
    #pragma unroll
    for (int j = 0; j < 4; ++j)
      #pragma unroll
      for (int r = 0; r < 4; ++r){
        const float p = exp2f((sv[j][r] - mi[r]) * LOG2E);
        const ushort_t pr = f2bf(p);
        pb16[j][r] = pr;
        rs[r] += bf2f(pr);
      }
    #pragma unroll
    for (int msk = 1; msk < 16; msk <<= 1)
      #pragma unroll
      for (int r = 0; r < 4; ++r)
        rs[r] += __shfl_xor(rs[r], msk);
    #pragma unroll
    for (int r = 0; r < 4; ++r) li[r] = li[r] * corr[r] + rs[r];
    #pragma unroll
    for (int j = 0; j < 4; ++j)
      #pragma unroll
      for (int r = 0; r < 4; ++r) ao[j][r] *= corr[r];

    // stage P (per-wave private region, swizzled)
    #pragma unroll
    for (int j = 0; j < 4; ++j)
      #pragma unroll
      for (int r = 0; r < 4; ++r){
        const int prow = rb + r;
        const int pcol = j*16 + rq;
        const int lb = prow*128 + pcol*2;
        const int pbb = lb ^ ((prow & 7) << 4);
        *(ushort_t*)((char*)&Ps[w][0] + pbb) = pb16[j][r];
      }
    asm volatile("" ::: "memory");
    // PV
    #pragma unroll
    for (int kk = 0; kk < 2; ++kk){
      const int lbp = rq*128 + (kk*32 + kg)*2;
      const int pbp = lbp ^ ((rq & 7) << 4);
      bf16x8 pf = *(const bf16x8*)((const char*)&Ps[w][0] + pbp);
      #pragma unroll
      for (int jd = 0; jd < 4; ++jd){
        const int drow = jd*16 + rq;
        const int lbv = drow*128 + (kk*32 + kg)*2;
        const int pbv = lbv ^ ((drow & 7) << 4);
        bf16x8 vf = *(const bf16x8*)((const char*)&Vts[cur][0] + pbv);
        ao[jd] = MFMA16(pf, vf, ao[jd]);
      }
    }
    if (kt + 1 < NT) writeV(cur ^ 1, vn);
    __syncthreads();
    cur ^= 1;
  }

  ushort_t* ob = attnb + (size_t)b * S_ * E_ + h * D_;
  #pragma unroll
  for (int jd = 0; jd < 4; ++jd)
    #pragma unroll
    for (int r = 0; r < 4; ++r){
      const int qrow = q0 + rb + r;
      const float o = ao[jd][r] / li[r];
      ob[(size_t)qrow * E_ + jd*16 + rq] = f2bf(o);
    }
}

// ---------------- LayerNorm ----------------

template<int WB>
__global__ __launch_bounds__(256)
void ln_kernel(const float* __restrict__ in, const float* __restrict__ gam,
               const float* __restrict__ bet, float* __restrict__ outf,
               ushort_t* __restrict__ outb)
{
  const int lane = threadIdx.x & 63;
  const size_t row = (size_t)blockIdx.x * 4 + (threadIdx.x >> 6);
  const float* xr = in + row * E_;
  const int e0 = lane * 8;
  float4 a = *(const float4*)(xr + e0);
  float4 c = *(const float4*)(xr + e0 + 4);
  float y[8] = {a.x,a.y,a.z,a.w,c.x,c.y,c.z,c.w};
  float s = 0.f, s2 = 0.f;
  #pragma unroll
  for (int i = 0; i < 8; ++i){ s += y[i]; s2 += y[i]*y[i]; }
  #pragma unroll
  for (int m = 1; m < 64; m <<= 1){ s += __shfl_xor(s, m); s2 += __shfl_xor(s2, m); }
  const float mu = s * (1.f / E_);
  const float rsd = rsqrtf(s2 * (1.f / E_) - mu*mu + 1e-5f);
  float4 G0 = *(const float4*)(gam + e0), G1 = *(const float4*)(gam + e0 + 4);
  float4 B0 = *(const float4*)(bet + e0), B1 = *(const float4*)(bet + e0 + 4);
  float gg[8] = {G0.x,G0.y,G0.z,G0.w,G1.x,G1.y,G1.z,G1.w};
  float bb[8] = {B0.x,B0.y,B0.z,B0.w,B1.x,B1.y,B1.z,B1.w};
  float o[8];
  #pragma unroll
  for (int i = 0; i < 8; ++i) o[i] = (y[i] - mu) * rsd * gg[i] + bb[i];
  float4 w0 = {o[0],o[1],o[2],o[3]}, w1 = {o[4],o[5],o[6],o[7]};
  *(float4*)(outf + row * E_ + e0) = w0;
  *(float4*)(outf + row * E_ + e0 + 4) = w1;
  if (WB){
    u16x8 ob;
    #pragma unroll
    for (int i = 0; i < 8; ++i) ob[i] = f2bf(o[i]);
    *(u16x8*)(outb + row * E_ + e0) = ob;
  }
}

// ---------------- launch ----------------

extern "C" void kernel_launch(void* const* d_in, const int* in_sizes, int n_in,
                              void* d_out, int out_size, void* d_ws, size_t ws_size,
                              hipStream_t stream)
{
  const float* x    = (const float*)d_in[0];
  const float* dist = (const float*)d_in[1];
  const int*   mask = (const int*)d_in[2];
  const float* Wq = (const float*)d_in[3];  const float* bq = (const float*)d_in[4];
  const float* Wk = (const float*)d_in[5];  const float* bk = (const float*)d_in[6];
  const float* Wv = (const float*)d_in[7];  const float* bv = (const float*)d_in[8];
  const float* Wo = (const float*)d_in[9];  const float* bo = (const float*)d_in[10];
  const float* W1 = (const float*)d_in[11]; const float* b1 = (const float*)d_in[12];
  const float* W2 = (const float*)d_in[13]; const float* b2 = (const float*)d_in[14];
  const float* g1 = (const float*)d_in[15]; const float* be1 = (const float*)d_in[16];
  const float* g2 = (const float*)d_in[17]; const float* be2 = (const float*)d_in[18];
  float* out = (float*)d_out;

  char* ws = (char*)d_ws;
  ushort_t* xb    = (ushort_t*)(ws + 0);          // 8,388,608
  ushort_t* wtqkv = (ushort_t*)(ws + 8388608);    // 1,572,864
  ushort_t* wto   = (ushort_t*)(ws + 9961472);    //   524,288
  ushort_t* wt1   = (ushort_t*)(ws + 10485760);   // 2,097,152
  ushort_t* wt2   = (ushort_t*)(ws + 12582912);   // 2,097,152
  float*    bqkv  = (float*)(ws + 14680064);      //     6,144
  ushort_t* qkvb  = (ushort_t*)(ws + 14686208);   // 25,165,824
  ushort_t* attnb = (ushort_t*)(ws + 39852032);   //  8,388,608
  ushort_t* f1    = (ushort_t*)(ws + 14686208);   // 33,554,432 (aliases qkvb+attnb, dead by then)
  float*    resid1= (float*)(ws + 48240640);      // 16,777,216
  float*    resid2= (float*)(ws + 48240640);      // aliases resid1 (dead by then)
  float*    hf    = (float*)(ws + 65017856);      // 16,777,216
  ushort_t* hb    = (ushort_t*)(ws + 81795072);   //  8,388,608  (total 90,183,680)

  k_cast_x<<<2048, 256, 0, stream>>>(x, xb);
  k_transpose<<<16*16, 256, 0, stream>>>(Wq, wtqkv + 0,      512, 512);
  k_transpose<<<16*16, 256, 0, stream>>>(Wk, wtqkv + 262144, 512, 512);
  k_transpose<<<16*16, 256, 0, stream>>>(Wv, wtqkv + 524288, 512, 512);
  k_transpose<<<16*16, 256, 0, stream>>>(Wo, wto, 512, 512);
  k_transpose<<<16*64, 256, 0, stream>>>(W1, wt1, 512, 2048);
  k_transpose<<<64*16, 256, 0, stream>>>(W2, wt2, 2048, 512);
  k_bias3<<<6, 256, 0, stream>>>(bq, bk, bv, bqkv);

  gemm_bt<0><<<64*12, 256, 0, stream>>>(xb, wtqkv, bqkv, nullptr, qkvb, M_, 1536, 512);
  attn_fused<<<1024, 256, 0, stream>>>(qkvb, dist, mask, attnb);
  gemm_bt<1><<<64*4, 256, 0, stream>>>(attnb, wto, bo, x, resid1, M_, 512, 512);
  ln_kernel<1><<<2048, 256, 0, stream>>>(resid1, g1, be1, hf, hb);
  gemm_bt<2><<<64*16, 256, 0, stream>>>(hb, wt1, b1, nullptr, f1, M_, 2048, 512);
  gemm_bt<1><<<64*4, 256, 0, stream>>>(f1, wt2, b2, hf, resid2, M_, 512, 2048);
  ln_kernel<0><<<2048, 256, 0, stream>>>(resid2, g2, be2, out, nullptr);
}

// Round 6
// 454.703 us; speedup vs baseline: 1.4037x; 1.4037x over previous
//
#include <hip/hip_runtime.h>

#define B_ 4
#define S_ 2048
#define E_ 512
#define H_ 8
#define D_ 64
#define DFF_ 2048
#define M_ (B_*S_)

typedef unsigned short ushort_t;
typedef __bf16 bf16x8 __attribute__((ext_vector_type(8)));
typedef unsigned short u16x8 __attribute__((ext_vector_type(8)));
typedef unsigned short u16x4 __attribute__((ext_vector_type(4)));
typedef float f32x4 __attribute__((ext_vector_type(4)));

__device__ __forceinline__ unsigned short f2bf(float f){
  unsigned int u = __builtin_bit_cast(unsigned int, f);
  unsigned int r = (u + 0x7fffu + ((u >> 16) & 1u)) >> 16;
  return (unsigned short)r;
}
__device__ __forceinline__ float bf2f(unsigned short h){
  unsigned int u = ((unsigned int)h) << 16;
  return __builtin_bit_cast(float, u);
}
__device__ __forceinline__ unsigned pack_bf16x2(float a, float b){
  return (unsigned)f2bf(a) | ((unsigned)f2bf(b) << 16);
}

#define GLD_LDS16(g, l) __builtin_amdgcn_global_load_lds( \
    (const __attribute__((address_space(1))) void*)(g),   \
    (__attribute__((address_space(3))) void*)(l), 16, 0, 0)

#define MFMA16(a, b, c) __builtin_amdgcn_mfma_f32_16x16x32_bf16((a), (b), (c), 0, 0, 0)

// ---------------- prep kernels ----------------

__global__ __launch_bounds__(256)
void k_cast_x(const float* __restrict__ x, ushort_t* __restrict__ xb){
  const size_t i = ((size_t)blockIdx.x * 256 + threadIdx.x) * 8;
  float4 a = *(const float4*)(x + i);
  float4 c = *(const float4*)(x + i + 4);
  float y[8] = {a.x,a.y,a.z,a.w,c.x,c.y,c.z,c.w};
  u16x8 o;
  #pragma unroll
  for (int j = 0; j < 8; ++j) o[j] = f2bf(y[j]);
  *(u16x8*)(xb + i) = o;
}

// distb[b][q][k] = bf16( mask[b][k] ? 0.4*dist[b][q][k] : -1e9 )
__global__ __launch_bounds__(256)
void prep_dist(const float* __restrict__ dist, const int* __restrict__ mask,
               ushort_t* __restrict__ distb){
  const size_t flat = ((size_t)blockIdx.x * 256 + threadIdx.x) * 8;
  const int b = (int)(flat >> 22);
  const int rem = (int)(flat & 4194303u);
  const int k0 = rem & 2047;
  float4 a = *(const float4*)(dist + flat);
  float4 c = *(const float4*)(dist + flat + 4);
  const int4* mp = (const int4*)(mask + b*S_ + k0);
  int4 m0 = mp[0], m1 = mp[1];
  float y[8] = {a.x,a.y,a.z,a.w,c.x,c.y,c.z,c.w};
  int  mm[8] = {m0.x,m0.y,m0.z,m0.w,m1.x,m1.y,m1.z,m1.w};
  u16x8 o;
  #pragma unroll
  for (int i = 0; i < 8; ++i) o[i] = f2bf(mm[i] ? 0.4f*y[i] : -1e9f);
  *(u16x8*)(distb + flat) = o;
}

// dst[n*K + k] = bf16(src[k*N + n])
__global__ __launch_bounds__(256)
void k_transpose(const float* __restrict__ src, ushort_t* __restrict__ dst, int K, int N){
  __shared__ float t[32][33];
  const int nbn = N >> 5;
  const int bk = blockIdx.x / nbn, bn = blockIdx.x - bk * nbn;
  const int tx = threadIdx.x & 31, ty = threadIdx.x >> 5;
  #pragma unroll
  for (int p = 0; p < 4; ++p)
    t[ty + p*8][tx] = src[(size_t)(bk*32 + ty + p*8) * N + bn*32 + tx];
  __syncthreads();
  #pragma unroll
  for (int p = 0; p < 4; ++p)
    dst[(size_t)(bn*32 + ty + p*8) * K + bk*32 + tx] = f2bf(t[tx][ty + p*8]);
}

__global__ __launch_bounds__(256)
void k_bias3(const float* __restrict__ a, const float* __restrict__ b,
             const float* __restrict__ c, float* __restrict__ o){
  int i = blockIdx.x * 256 + threadIdx.x;
  if (i < 512) o[i] = a[i];
  else if (i < 1024) o[i] = b[i - 512];
  else if (i < 1536) o[i] = c[i - 1024];
}

// ---------------- GEMM: C[M,N] = A[M,K](bf16) @ Bt[N,K](bf16)^T ----------------

template<int MODE>
__global__ __launch_bounds__(256)
void gemm_bt(const ushort_t* __restrict__ A, const ushort_t* __restrict__ Bt,
             const float* __restrict__ bias, const float* __restrict__ resid,
             void* __restrict__ out, int Md, int Nd, int Kd)
{
  __shared__ ushort_t sm[2][2][128*32];
  const int tid = threadIdx.x;
  const int lane = tid & 63, wid = tid >> 6;
  const int wr = wid >> 1, wc = wid & 1;
  const int nbn = Nd >> 7;
  const int bm = blockIdx.x / nbn;
  const int bn = blockIdx.x - bm * nbn;
  const int rq = lane & 15, kg = (lane >> 4) << 3;

  f32x4 acc[4][4];
  #pragma unroll
  for (int i = 0; i < 4; ++i)
    #pragma unroll
    for (int j = 0; j < 4; ++j) acc[i][j] = (f32x4){0.f,0.f,0.f,0.f};

  const int nkt = Kd >> 5;
  const int c0 = tid, c1 = tid + 256;
  const int rA0 = c0 >> 2, koA0 = (c0 & 3) << 3;
  const int rA1 = c1 >> 2, koA1 = (c1 & 3) << 3;
  const ushort_t* Abase = A + (size_t)(bm * 128) * Kd;
  const ushort_t* Bbase = Bt + (size_t)(bn * 128) * Kd;

  auto stage = [&](int buf, int kt){
    const int k0 = kt << 5;
    GLD_LDS16(Abase + (size_t)rA0 * Kd + k0 + koA0, &sm[buf][0][c0 * 8]);
    GLD_LDS16(Abase + (size_t)rA1 * Kd + k0 + koA1, &sm[buf][0][c1 * 8]);
    GLD_LDS16(Bbase + (size_t)rA0 * Kd + k0 + koA0, &sm[buf][1][c0 * 8]);
    GLD_LDS16(Bbase + (size_t)rA1 * Kd + k0 + koA1, &sm[buf][1][c1 * 8]);
  };

  stage(0, 0);
  __syncthreads();
  int cur = 0;
  for (int kt = 0; kt < nkt; ++kt){
    if (kt + 1 < nkt) stage(cur ^ 1, kt + 1);
    const ushort_t* As = &sm[cur][0][0];
    const ushort_t* Bs = &sm[cur][1][0];
    bf16x8 af[4], bfr[4];
    #pragma unroll
    for (int i = 0; i < 4; ++i) af[i]  = *(const bf16x8*)&As[(wr*64 + i*16 + rq)*32 + kg];
    #pragma unroll
    for (int j = 0; j < 4; ++j) bfr[j] = *(const bf16x8*)&Bs[(wc*64 + j*16 + rq)*32 + kg];
    #pragma unroll
    for (int i = 0; i < 4; ++i)
      #pragma unroll
      for (int j = 0; j < 4; ++j)
        acc[i][j] = MFMA16(af[i], bfr[j], acc[i][j]);
    __syncthreads();
    cur ^= 1;
  }

  const int rb = (lane >> 4) << 2;
  #pragma unroll
  for (int i = 0; i < 4; ++i){
    #pragma unroll
    for (int j = 0; j < 4; ++j){
      const int col = bn*128 + wc*64 + j*16 + rq;
      const float bs = bias[col];
      #pragma unroll
      for (int r = 0; r < 4; ++r){
        const int row = bm*128 + wr*64 + i*16 + rb + r;
        const float v = acc[i][j][r] + bs;
        if (MODE == 0){
          ushort_t* o = (ushort_t*)out;
          const int which = col >> 9, hd = col & 511;
          const int hh = hd >> 6, dd = hd & 63;
          const int bb = row >> 11, ss = row & 2047;
          o[(size_t)which*(B_*H_*S_*D_) + (((size_t)(bb*H_ + hh))*S_ + ss)*D_ + dd] = f2bf(v);
        } else if (MODE == 1){
          float* o = (float*)out;
          o[(size_t)row*Nd + col] = v + resid[(size_t)row*Nd + col];
        } else {
          ushort_t* o = (ushort_t*)out;
          o[(size_t)row*Nd + col] = f2bf(fmaxf(v, 0.f));
        }
      }
    }
  }
}

// ---------------- fused flash attention (swapped-QK^T layout) ----------------
// qkv: q,k,v each [B,H,S,D] bf16. distb: [B,S,S] bf16 (mask+0.4 folded).

__global__ __launch_bounds__(256)
void attn_fused(const ushort_t* __restrict__ qkv,
                const ushort_t* __restrict__ distb,
                ushort_t* __restrict__ attnb)
{
  __shared__ ushort_t Ks [2][64*64];
  __shared__ ushort_t Vts[2][64*64];
  __shared__ ushort_t Ds [2][64*64];
  __shared__ ushort_t Ps [4][16*64];

  const int tid = threadIdx.x, lane = tid & 63, w = tid >> 6;
  const int blk = blockIdx.x;
  const int h = blk & 7, qt = (blk >> 3) & 31, b = blk >> 8;
  const size_t plane = (size_t)S_ * D_;
  const ushort_t* Q  = qkv + (size_t)(b*H_ + h) * plane;
  const ushort_t* Kg = Q + (size_t)B_*H_*plane;
  const ushort_t* Vg = Q + 2 * (size_t)B_*H_*plane;
  const ushort_t* distq = distb + (size_t)b * S_ * S_;

  const int rq = lane & 15, g = lane >> 4;
  const int q0b = qt * 64;
  const int q0 = q0b + w*16;
  const float LOG2E = 1.4426950408889634f;

  // Q B-fragment: lane holds Q[q0+rq][kk*32 + g*8 .. +7]
  bf16x8 qf[2];
  #pragma unroll
  for (int kk = 0; kk < 2; ++kk)
    qf[kk] = *(const bf16x8*)&Q[(size_t)(q0 + rq)*D_ + kk*32 + g*8];

  f32x4 ao[4];
  #pragma unroll
  for (int j = 0; j < 4; ++j) ao[j] = (f32x4){0.f,0.f,0.f,0.f};
  float mi = -1e30f, li = 0.f;

  const int cK0 = tid, cK1 = tid + 256;
  auto stageK = [&](int buf, int kt){
    const char* Kt = (const char*)(Kg + (size_t)kt * 64 * D_);
    const int pb0 = cK0 * 16, pb1 = cK1 * 16;
    const int lb0 = pb0 ^ ((((unsigned)pb0 >> 7) & 7) << 4);
    const int lb1 = pb1 ^ ((((unsigned)pb1 >> 7) & 7) << 4);
    GLD_LDS16(Kt + lb0, (char*)&Ks[buf][0] + pb0);
    GLD_LDS16(Kt + lb1, (char*)&Ks[buf][0] + pb1);
  };
  auto stageD = [&](int buf, int kt){
    #pragma unroll
    for (int hh = 0; hh < 2; ++hh){
      const int pbd = (tid + hh*256) * 16;
      const int qrl = pbd >> 7;   // local q row 0..63
      const int lbd = pbd ^ (((pbd >> 7) & 7) << 4);
      const char* src = (const char*)(distq + (size_t)(q0b + qrl) * S_ + kt*64) + (lbd & 127);
      GLD_LDS16(src, (char*)&Ds[buf][0] + pbd);
    }
  };
  auto loadV = [&](int kt, u16x8* vr){
    const ushort_t* Vt = Vg + (size_t)kt * 64 * D_;
    vr[0] = *(const u16x8*)&Vt[cK0 * 8];
    vr[1] = *(const u16x8*)&Vt[cK1 * 8];
  };
  auto writeV = [&](int buf, const u16x8* vr){
    #pragma unroll
    for (int hh = 0; hh < 2; ++hh){
      const int c = tid + hh * 256;
      const int key = c >> 3, d0 = (c & 7) << 3;
      #pragma unroll
      for (int i2 = 0; i2 < 8; ++i2){
        const int dd = d0 + i2;
        const int lb = dd * 128 + key * 2;
        const int pb = lb ^ ((dd & 7) << 4);
        *(ushort_t*)((char*)&Vts[buf][0] + pb) = vr[hh][i2];
      }
    }
  };

  u16x8 vr0[2];
  stageK(0, 0);
  stageD(0, 0);
  loadV(0, vr0);
  writeV(0, vr0);
  __syncthreads();

  int cur = 0;
  const int NT = S_ / 64;
  for (int kt = 0; kt < NT; ++kt){
    u16x8 vn[2];
    if (kt + 1 < NT){
      loadV(kt + 1, vn);
      stageK(cur ^ 1, kt + 1);
      stageD(cur ^ 1, kt + 1);
    }
    // dist bias: lane needs Ds[w*16 + rq][j*16 + g*4 .. +3]
    u16x4 dv[4];
    #pragma unroll
    for (int j = 0; j < 4; ++j){
      const int logical = (w*16 + rq)*128 + j*32 + g*8;
      const int phys = logical ^ ((rq & 7) << 4);
      dv[j] = *(const u16x4*)((const char*)&Ds[cur][0] + phys);
    }
    // S^T = K @ Q^T : lane owns q-row q0+rq; regs span keys j*16 + g*4 + r
    f32x4 sc[4];
    #pragma unroll
    for (int j = 0; j < 4; ++j) sc[j] = (f32x4){0.f,0.f,0.f,0.f};
    __builtin_amdgcn_s_setprio(1);
    #pragma unroll
    for (int kk = 0; kk < 2; ++kk){
      #pragma unroll
      for (int j = 0; j < 4; ++j){
        const int phys = ((j*16 + rq)*128 + kk*64 + g*16) ^ ((rq & 7) << 4);
        bf16x8 kf = *(const bf16x8*)((const char*)&Ks[cur][0] + phys);
        sc[j] = MFMA16(kf, qf[kk], sc[j]);
      }
    }
    __builtin_amdgcn_s_setprio(0);
    // scores + bias (mask folded into bias)
    float sv[4][4];
    #pragma unroll
    for (int j = 0; j < 4; ++j)
      #pragma unroll
      for (int r = 0; r < 4; ++r)
        sv[j][r] = fmaf(sc[j][r], 0.125f, bf2f(dv[j][r]));
    // per-lane (one q-row) max over 16 + cross-group
    float pm = sv[0][0];
    #pragma unroll
    for (int j = 0; j < 4; ++j)
      #pragma unroll
      for (int r = 0; r < 4; ++r) pm = fmaxf(pm, sv[j][r]);
    pm = fmaxf(pm, __shfl_xor(pm, 16));
    pm = fmaxf(pm, __shfl_xor(pm, 32));
    // defer-max rescale
    const int allskip = __all(pm <= mi + 8.f);
    if (!allskip){
      const float mn = fmaxf(mi, pm);
      const float corr = exp2f((mi - mn) * LOG2E);
      mi = mn;
      li *= corr;
      #pragma unroll
      for (int r = 0; r < 4; ++r){
        const int ci = __builtin_amdgcn_ds_bpermute((g*4 + r) << 2,
                         __builtin_bit_cast(int, corr));
        const float c4 = __builtin_bit_cast(float, ci);
        #pragma unroll
        for (int jd = 0; jd < 4; ++jd) ao[jd][r] *= c4;
      }
    }
    // P = exp(S - m), in-lane row sum
    const float mL = mi * LOG2E;
    float p[4][4];
    float rs = 0.f;
    #pragma unroll
    for (int j = 0; j < 4; ++j)
      #pragma unroll
      for (int r = 0; r < 4; ++r){
        p[j][r] = exp2f(fmaf(sv[j][r], LOG2E, -mL));
        rs += p[j][r];
      }
    rs += __shfl_xor(rs, 16);
    rs += __shfl_xor(rs, 32);
    li += rs;
    // stage P -> Ps[w][qrow=rq][key] (swizzled), paired bf16 writes
    #pragma unroll
    for (int j = 0; j < 4; ++j)
      #pragma unroll
      for (int t = 0; t < 2; ++t){
        const unsigned u = pack_bf16x2(p[j][2*t], p[j][2*t + 1]);
        const int logical = rq*128 + j*32 + g*8 + t*4;
        const int phys = logical ^ ((rq & 7) << 4);
        *(unsigned*)((char*)&Ps[w][0] + phys) = u;
      }
    asm volatile("s_waitcnt lgkmcnt(0)" ::: "memory");
    __builtin_amdgcn_sched_barrier(0);
    // PV: A = P (rows qrow), B = V^T (cols d)
    __builtin_amdgcn_s_setprio(1);
    #pragma unroll
    for (int kk = 0; kk < 2; ++kk){
      const int physp = (rq*128 + kk*64 + g*16) ^ ((rq & 7) << 4);
      bf16x8 pf = *(const bf16x8*)((const char*)&Ps[w][0] + physp);
      #pragma unroll
      for (int jd = 0; jd < 4; ++jd){
        const int drow = jd*16 + rq;
        const int physv = (drow*128 + kk*64 + g*16) ^ ((rq & 7) << 4);
        bf16x8 vf = *(const bf16x8*)((const char*)&Vts[cur][0] + physv);
        ao[jd] = MFMA16(pf, vf, ao[jd]);
      }
    }
    __builtin_amdgcn_s_setprio(0);
    if (kt + 1 < NT) writeV(cur ^ 1, vn);
    __syncthreads();
    cur ^= 1;
  }

  // output rows q0 + g*4 + r, cols jd*16 + rq
  ushort_t* ob = attnb + (size_t)b * S_ * E_ + h * D_;
  float inv[4];
  #pragma unroll
  for (int r = 0; r < 4; ++r){
    const int li_i = __builtin_amdgcn_ds_bpermute((g*4 + r) << 2,
                       __builtin_bit_cast(int, li));
    inv[r] = 1.f / __builtin_bit_cast(float, li_i);
  }
  #pragma unroll
  for (int jd = 0; jd < 4; ++jd)
    #pragma unroll
    for (int r = 0; r < 4; ++r){
      const int qrow = q0 + g*4 + r;
      ob[(size_t)qrow * E_ + jd*16 + rq] = f2bf(ao[jd][r] * inv[r]);
    }
}

// ---------------- LayerNorm ----------------

template<int WB>
__global__ __launch_bounds__(256)
void ln_kernel(const float* __restrict__ in, const float* __restrict__ gam,
               const float* __restrict__ bet, float* __restrict__ outf,
               ushort_t* __restrict__ outb)
{
  const int lane = threadIdx.x & 63;
  const size_t row = (size_t)blockIdx.x * 4 + (threadIdx.x >> 6);
  const float* xr = in + row * E_;
  const int e0 = lane * 8;
  float4 a = *(const float4*)(xr + e0);
  float4 c = *(const float4*)(xr + e0 + 4);
  float y[8] = {a.x,a.y,a.z,a.w,c.x,c.y,c.z,c.w};
  float s = 0.f, s2 = 0.f;
  #pragma unroll
  for (int i = 0; i < 8; ++i){ s += y[i]; s2 += y[i]*y[i]; }
  #pragma unroll
  for (int m = 1; m < 64; m <<= 1){ s += __shfl_xor(s, m); s2 += __shfl_xor(s2, m); }
  const float mu = s * (1.f / E_);
  const float rsd = rsqrtf(s2 * (1.f / E_) - mu*mu + 1e-5f);
  float4 G0 = *(const float4*)(gam + e0), G1 = *(const float4*)(gam + e0 + 4);
  float4 B0 = *(const float4*)(bet + e0), B1 = *(const float4*)(bet + e0 + 4);
  float gg[8] = {G0.x,G0.y,G0.z,G0.w,G1.x,G1.y,G1.z,G1.w};
  float bb[8] = {B0.x,B0.y,B0.z,B0.w,B1.x,B1.y,B1.z,B1.w};
  float o[8];
  #pragma unroll
  for (int i = 0; i < 8; ++i) o[i] = (y[i] - mu) * rsd * gg[i] + bb[i];
  float4 w0 = {o[0],o[1],o[2],o[3]}, w1 = {o[4],o[5],o[6],o[7]};
  *(float4*)(outf + row * E_ + e0) = w0;
  *(float4*)(outf + row * E_ + e0 + 4) = w1;
  if (WB){
    u16x8 ob;
    #pragma unroll
    for (int i = 0; i < 8; ++i) ob[i] = f2bf(o[i]);
    *(u16x8*)(outb + row * E_ + e0) = ob;
  }
}

// ---------------- launch ----------------

extern "C" void kernel_launch(void* const* d_in, const int* in_sizes, int n_in,
                              void* d_out, int out_size, void* d_ws, size_t ws_size,
                              hipStream_t stream)
{
  const float* x    = (const float*)d_in[0];
  const float* dist = (const float*)d_in[1];
  const int*   mask = (const int*)d_in[2];
  const float* Wq = (const float*)d_in[3];  const float* bq = (const float*)d_in[4];
  const float* Wk = (const float*)d_in[5];  const float* bk = (const float*)d_in[6];
  const float* Wv = (const float*)d_in[7];  const float* bv = (const float*)d_in[8];
  const float* Wo = (const float*)d_in[9];  const float* bo = (const float*)d_in[10];
  const float* W1 = (const float*)d_in[11]; const float* b1 = (const float*)d_in[12];
  const float* W2 = (const float*)d_in[13]; const float* b2 = (const float*)d_in[14];
  const float* g1 = (const float*)d_in[15]; const float* be1 = (const float*)d_in[16];
  const float* g2 = (const float*)d_in[17]; const float* be2 = (const float*)d_in[18];
  float* out = (float*)d_out;

  char* ws = (char*)d_ws;
  ushort_t* xb    = (ushort_t*)(ws + 0);          // 8,388,608
  ushort_t* wtqkv = (ushort_t*)(ws + 8388608);    // 1,572,864
  ushort_t* wto   = (ushort_t*)(ws + 9961472);    //   524,288
  ushort_t* wt1   = (ushort_t*)(ws + 10485760);   // 2,097,152
  ushort_t* wt2   = (ushort_t*)(ws + 12582912);   // 2,097,152
  float*    bqkv  = (float*)(ws + 14680064);      //     6,144
  ushort_t* qkvb  = (ushort_t*)(ws + 14686208);   // 25,165,824
  ushort_t* attnb = (ushort_t*)(ws + 39852032);   //  8,388,608
  ushort_t* f1    = (ushort_t*)(ws + 14686208);   // 33,554,432 (aliases qkvb+attnb, dead by then)
  // distb aliases resid1+hf (both first written AFTER attention completes)
  ushort_t* distb = (ushort_t*)(ws + 48240640);   // 33,554,432
  float*    resid1= (float*)(ws + 48240640);      // 16,777,216
  float*    resid2= (float*)(ws + 48240640);      // aliases resid1 (dead by then)
  float*    hf    = (float*)(ws + 65017856);      // 16,777,216
  ushort_t* hb    = (ushort_t*)(ws + 81795072);   //  8,388,608  (total 90,183,680)

  k_cast_x<<<2048, 256, 0, stream>>>(x, xb);
  prep_dist<<<8192, 256, 0, stream>>>(dist, mask, distb);
  k_transpose<<<16*16, 256, 0, stream>>>(Wq, wtqkv + 0,      512, 512);
  k_transpose<<<16*16, 256, 0, stream>>>(Wk, wtqkv + 262144, 512, 512);
  k_transpose<<<16*16, 256, 0, stream>>>(Wv, wtqkv + 524288, 512, 512);
  k_transpose<<<16*16, 256, 0, stream>>>(Wo, wto, 512, 512);
  k_transpose<<<16*64, 256, 0, stream>>>(W1, wt1, 512, 2048);
  k_transpose<<<64*16, 256, 0, stream>>>(W2, wt2, 2048, 512);
  k_bias3<<<6, 256, 0, stream>>>(bq, bk, bv, bqkv);

  gemm_bt<0><<<64*12, 256, 0, stream>>>(xb, wtqkv, bqkv, nullptr, qkvb, M_, 1536, 512);
  attn_fused<<<1024, 256, 0, stream>>>(qkvb, distb, attnb);
  gemm_bt<1><<<64*4, 256, 0, stream>>>(attnb, wto, bo, x, resid1, M_, 512, 512);
  ln_kernel<1><<<2048, 256, 0, stream>>>(resid1, g1, be1, hf, hb);
  gemm_bt<2><<<64*16, 256, 0, stream>>>(hb, wt1, b1, nullptr, f1, M_, 2048, 512);
  gemm_bt<1><<<64*4, 256, 0, stream>>>(f1, wt2, b2, hf, resid2, M_, 512, 2048);
  ln_kernel<0><<<2048, 256, 0, stream>>>(resid2, g2, be2, out, nullptr);
}

// Round 7
// 406.048 us; speedup vs baseline: 1.5719x; 1.1198x over previous
//
#include <hip/hip_runtime.h>

#define B_ 4
#define S_ 2048
#define E_ 512
#define H_ 8
#define D_ 64
#define DFF_ 2048
#define M_ (B_*S_)

typedef unsigned short ushort_t;
typedef __bf16 bf16x8 __attribute__((ext_vector_type(8)));
typedef unsigned short u16x8 __attribute__((ext_vector_type(8)));
typedef unsigned short u16x4 __attribute__((ext_vector_type(4)));
typedef unsigned u32x2 __attribute__((ext_vector_type(2)));
typedef float f32x4 __attribute__((ext_vector_type(4)));

__device__ __forceinline__ unsigned short f2bf(float f){
  unsigned int u = __builtin_bit_cast(unsigned int, f);
  unsigned int r = (u + 0x7fffu + ((u >> 16) & 1u)) >> 16;
  return (unsigned short)r;
}
__device__ __forceinline__ float bf2f(unsigned short h){
  unsigned int u = ((unsigned int)h) << 16;
  return __builtin_bit_cast(float, u);
}
__device__ __forceinline__ unsigned pack_bf16x2(float a, float b){
  return (unsigned)f2bf(a) | ((unsigned)f2bf(b) << 16);
}

#define GLD_LDS16(g, l) __builtin_amdgcn_global_load_lds( \
    (const __attribute__((address_space(1))) void*)(g),   \
    (__attribute__((address_space(3))) void*)(l), 16, 0, 0)

#define MFMA16(a, b, c) __builtin_amdgcn_mfma_f32_16x16x32_bf16((a), (b), (c), 0, 0, 0)

// ---------------- prep kernels ----------------

__global__ __launch_bounds__(256)
void k_cast_x(const float* __restrict__ x, ushort_t* __restrict__ xb){
  const size_t i = ((size_t)blockIdx.x * 256 + threadIdx.x) * 8;
  float4 a = *(const float4*)(x + i);
  float4 c = *(const float4*)(x + i + 4);
  float y[8] = {a.x,a.y,a.z,a.w,c.x,c.y,c.z,c.w};
  u16x8 o;
  #pragma unroll
  for (int j = 0; j < 8; ++j) o[j] = f2bf(y[j]);
  *(u16x8*)(xb + i) = o;
}

// distb[b][q][k] = bf16( mask[b][k] ? 0.4*dist[b][q][k] : -1e9 )
__global__ __launch_bounds__(256)
void prep_dist(const float* __restrict__ dist, const int* __restrict__ mask,
               ushort_t* __restrict__ distb){
  const size_t flat = ((size_t)blockIdx.x * 256 + threadIdx.x) * 8;
  const int b = (int)(flat >> 22);
  const int rem = (int)(flat & 4194303u);
  const int k0 = rem & 2047;
  float4 a = *(const float4*)(dist + flat);
  float4 c = *(const float4*)(dist + flat + 4);
  const int4* mp = (const int4*)(mask + b*S_ + k0);
  int4 m0 = mp[0], m1 = mp[1];
  float y[8] = {a.x,a.y,a.z,a.w,c.x,c.y,c.z,c.w};
  int  mm[8] = {m0.x,m0.y,m0.z,m0.w,m1.x,m1.y,m1.z,m1.w};
  u16x8 o;
  #pragma unroll
  for (int i = 0; i < 8; ++i) o[i] = f2bf(mm[i] ? 0.4f*y[i] : -1e9f);
  *(u16x8*)(distb + flat) = o;
}

// dst[n*K + k] = bf16(src[k*N + n])
__global__ __launch_bounds__(256)
void k_transpose(const float* __restrict__ src, ushort_t* __restrict__ dst, int K, int N){
  __shared__ float t[32][33];
  const int nbn = N >> 5;
  const int bk = blockIdx.x / nbn, bn = blockIdx.x - bk * nbn;
  const int tx = threadIdx.x & 31, ty = threadIdx.x >> 5;
  #pragma unroll
  for (int p = 0; p < 4; ++p)
    t[ty + p*8][tx] = src[(size_t)(bk*32 + ty + p*8) * N + bn*32 + tx];
  __syncthreads();
  #pragma unroll
  for (int p = 0; p < 4; ++p)
    dst[(size_t)(bn*32 + ty + p*8) * K + bk*32 + tx] = f2bf(t[tx][ty + p*8]);
}

__global__ __launch_bounds__(256)
void k_bias3(const float* __restrict__ a, const float* __restrict__ b,
             const float* __restrict__ c, float* __restrict__ o){
  int i = blockIdx.x * 256 + threadIdx.x;
  if (i < 512) o[i] = a[i];
  else if (i < 1024) o[i] = b[i - 512];
  else if (i < 1536) o[i] = c[i - 1024];
}

// ---------------- GEMM: C[M,N] = A[M,K](bf16) @ Bt[N,K](bf16)^T ----------------

template<int MODE>
__global__ __launch_bounds__(256)
void gemm_bt(const ushort_t* __restrict__ A, const ushort_t* __restrict__ Bt,
             const float* __restrict__ bias, const float* __restrict__ resid,
             void* __restrict__ out, int Md, int Nd, int Kd)
{
  __shared__ ushort_t sm[2][2][128*32];
  const int tid = threadIdx.x;
  const int lane = tid & 63, wid = tid >> 6;
  const int wr = wid >> 1, wc = wid & 1;
  const int nbn = Nd >> 7;
  const int bm = blockIdx.x / nbn;
  const int bn = blockIdx.x - bm * nbn;
  const int rq = lane & 15, kg = (lane >> 4) << 3;

  f32x4 acc[4][4];
  #pragma unroll
  for (int i = 0; i < 4; ++i)
    #pragma unroll
    for (int j = 0; j < 4; ++j) acc[i][j] = (f32x4){0.f,0.f,0.f,0.f};

  const int nkt = Kd >> 5;
  const int c0 = tid, c1 = tid + 256;
  const int rA0 = c0 >> 2, koA0 = (c0 & 3) << 3;
  const int rA1 = c1 >> 2, koA1 = (c1 & 3) << 3;
  const ushort_t* Abase = A + (size_t)(bm * 128) * Kd;
  const ushort_t* Bbase = Bt + (size_t)(bn * 128) * Kd;

  auto stage = [&](int buf, int kt){
    const int k0 = kt << 5;
    GLD_LDS16(Abase + (size_t)rA0 * Kd + k0 + koA0, &sm[buf][0][c0 * 8]);
    GLD_LDS16(Abase + (size_t)rA1 * Kd + k0 + koA1, &sm[buf][0][c1 * 8]);
    GLD_LDS16(Bbase + (size_t)rA0 * Kd + k0 + koA0, &sm[buf][1][c0 * 8]);
    GLD_LDS16(Bbase + (size_t)rA1 * Kd + k0 + koA1, &sm[buf][1][c1 * 8]);
  };

  stage(0, 0);
  __syncthreads();
  int cur = 0;
  for (int kt = 0; kt < nkt; ++kt){
    if (kt + 1 < nkt) stage(cur ^ 1, kt + 1);
    const ushort_t* As = &sm[cur][0][0];
    const ushort_t* Bs = &sm[cur][1][0];
    bf16x8 af[4], bfr[4];
    #pragma unroll
    for (int i = 0; i < 4; ++i) af[i]  = *(const bf16x8*)&As[(wr*64 + i*16 + rq)*32 + kg];
    #pragma unroll
    for (int j = 0; j < 4; ++j) bfr[j] = *(const bf16x8*)&Bs[(wc*64 + j*16 + rq)*32 + kg];
    #pragma unroll
    for (int i = 0; i < 4; ++i)
      #pragma unroll
      for (int j = 0; j < 4; ++j)
        acc[i][j] = MFMA16(af[i], bfr[j], acc[i][j]);
    __syncthreads();
    cur ^= 1;
  }

  const int rb = (lane >> 4) << 2;
  #pragma unroll
  for (int i = 0; i < 4; ++i){
    #pragma unroll
    for (int j = 0; j < 4; ++j){
      const int col = bn*128 + wc*64 + j*16 + rq;
      const float bs = bias[col];
      #pragma unroll
      for (int r = 0; r < 4; ++r){
        const int row = bm*128 + wr*64 + i*16 + rb + r;
        const float v = acc[i][j][r] + bs;
        if (MODE == 0){
          ushort_t* o = (ushort_t*)out;
          const int which = col >> 9, hd = col & 511;
          const int hh = hd >> 6, dd = hd & 63;
          const int bb = row >> 11, ss = row & 2047;
          o[(size_t)which*(B_*H_*S_*D_) + (((size_t)(bb*H_ + hh))*S_ + ss)*D_ + dd] = f2bf(v);
        } else if (MODE == 1){
          float* o = (float*)out;
          o[(size_t)row*Nd + col] = v + resid[(size_t)row*Nd + col];
        } else {
          ushort_t* o = (ushort_t*)out;
          o[(size_t)row*Nd + col] = f2bf(fmaxf(v, 0.f));
        }
      }
    }
  }
}

// ---------------- fused flash attention (swapped-QK^T layout) ----------------
// qkv: q,k,v each [B,H,S,D] bf16. distb: [B,S,S] bf16 (mask+0.4 folded).

__global__ __launch_bounds__(256, 4)
void attn_fused(const ushort_t* __restrict__ qkv,
                const ushort_t* __restrict__ distb,
                ushort_t* __restrict__ attnb)
{
  __shared__ ushort_t Ks [2][64*64];   // 16 KB
  __shared__ ushort_t Vts[2][64*64];   // 16 KB (V^T: [d][key])
  __shared__ ushort_t Ps [4][16*64];   //  8 KB

  const int tid = threadIdx.x, lane = tid & 63, w = tid >> 6;
  const int blk = blockIdx.x;
  const int h = blk & 7, qt = (blk >> 3) & 31, b = blk >> 8;
  const size_t plane = (size_t)S_ * D_;
  const ushort_t* Q  = qkv + (size_t)(b*H_ + h) * plane;
  const ushort_t* Kg = Q + (size_t)B_*H_*plane;
  const ushort_t* Vg = Q + 2 * (size_t)B_*H_*plane;
  const ushort_t* distq = distb + (size_t)b * S_ * S_;

  const int rq = lane & 15, g = lane >> 4;
  const int q0b = qt * 64;
  const int q0 = q0b + w*16;
  const float LOG2E = 1.4426950408889634f;

  // Q B-fragment: lane holds Q[q0+rq][kk*32 + g*8 .. +7]
  bf16x8 qf[2];
  #pragma unroll
  for (int kk = 0; kk < 2; ++kk)
    qf[kk] = *(const bf16x8*)&Q[(size_t)(q0 + rq)*D_ + kk*32 + g*8];

  f32x4 ao[4];
  #pragma unroll
  for (int j = 0; j < 4; ++j) ao[j] = (f32x4){0.f,0.f,0.f,0.f};
  float mi = -1e30f, li = 0.f;

  const int cK0 = tid, cK1 = tid + 256;
  auto stageK = [&](int buf, int kt){
    const char* Kt = (const char*)(Kg + (size_t)kt * 64 * D_);
    const int pb0 = cK0 * 16, pb1 = cK1 * 16;
    const int lb0 = pb0 ^ ((((unsigned)pb0 >> 7) & 7) << 4);
    const int lb1 = pb1 ^ ((((unsigned)pb1 >> 7) & 7) << 4);
    GLD_LDS16(Kt + lb0, (char*)&Ks[buf][0] + pb0);
    GLD_LDS16(Kt + lb1, (char*)&Ks[buf][0] + pb1);
  };
  // V: thread (kp=tid&31, ds8=tid>>5) loads rows 2kp,2kp+1 at d-seg ds8
  const int kp = tid & 31, ds8 = tid >> 5;
  auto loadV = [&](int kt, u16x8* vr){
    const ushort_t* Vt = Vg + (size_t)kt * 64 * D_;
    vr[0] = *(const u16x8*)&Vt[(2*kp)     * D_ + ds8*8];
    vr[1] = *(const u16x8*)&Vt[(2*kp + 1) * D_ + ds8*8];
  };
  // conflict-free transpose write: 8x ds_write_b32, banks = kp ^ const
  auto writeV = [&](int buf, const u16x8* vr){
    #pragma unroll
    for (int e = 0; e < 8; ++e){
      const int d = ds8*8 + e;
      const unsigned u = (unsigned)vr[0][e] | ((unsigned)vr[1][e] << 16);
      const int lb = d*128 + kp*4;
      const int pb = lb ^ ((d & 7) << 4);
      *(unsigned*)((char*)&Vts[buf][0] + pb) = u;
    }
  };
  // dist bias straight to registers: lane (g,rq) needs keys j*16+g*4..+3 of row q0+rq
  auto loadD = [&](int kt, u16x4* dr){
    const ushort_t* Dp = distq + (size_t)(q0 + rq) * S_ + kt*64;
    #pragma unroll
    for (int j = 0; j < 4; ++j)
      dr[j] = *(const u16x4*)&Dp[j*16 + g*4];
  };

  u16x8 vr0[2];
  u16x4 dv[4], dvn[4];
  stageK(0, 0);
  loadV(0, vr0);
  loadD(0, dv);
  writeV(0, vr0);
  __syncthreads();

  int cur = 0;
  const int NT = S_ / 64;
  for (int kt = 0; kt < NT; ++kt){
    u16x8 vn[2];
    if (kt + 1 < NT){
      loadV(kt + 1, vn);
      stageK(cur ^ 1, kt + 1);
      loadD(kt + 1, dvn);
    }
    // S^T = K @ Q^T : lane owns q-row q0+rq; regs span keys j*16 + g*4 + r
    f32x4 sc[4];
    #pragma unroll
    for (int j = 0; j < 4; ++j) sc[j] = (f32x4){0.f,0.f,0.f,0.f};
    __builtin_amdgcn_s_setprio(1);
    #pragma unroll
    for (int kk = 0; kk < 2; ++kk){
      #pragma unroll
      for (int j = 0; j < 4; ++j){
        const int phys = ((j*16 + rq)*128 + kk*64 + g*16) ^ ((rq & 7) << 4);
        bf16x8 kf = *(const bf16x8*)((const char*)&Ks[cur][0] + phys);
        sc[j] = MFMA16(kf, qf[kk], sc[j]);
      }
    }
    __builtin_amdgcn_s_setprio(0);
    // scores + bias (mask folded into bias)
    float sv[4][4];
    #pragma unroll
    for (int j = 0; j < 4; ++j)
      #pragma unroll
      for (int r = 0; r < 4; ++r)
        sv[j][r] = fmaf(sc[j][r], 0.125f, bf2f(dv[j][r]));
    // per-lane (one q-row) max over 16 + cross-group
    float pm = sv[0][0];
    #pragma unroll
    for (int j = 0; j < 4; ++j)
      #pragma unroll
      for (int r = 0; r < 4; ++r) pm = fmaxf(pm, sv[j][r]);
    pm = fmaxf(pm, __shfl_xor(pm, 16));
    pm = fmaxf(pm, __shfl_xor(pm, 32));
    // defer-max rescale
    const int allskip = __all(pm <= mi + 8.f);
    if (!allskip){
      const float mn = fmaxf(mi, pm);
      const float corr = exp2f((mi - mn) * LOG2E);
      mi = mn;
      li *= corr;
      #pragma unroll
      for (int r = 0; r < 4; ++r){
        const int ci = __builtin_amdgcn_ds_bpermute((g*4 + r) << 2,
                         __builtin_bit_cast(int, corr));
        const float c4 = __builtin_bit_cast(float, ci);
        #pragma unroll
        for (int jd = 0; jd < 4; ++jd) ao[jd][r] *= c4;
      }
    }
    // P = exp(S - m), in-lane row sum
    const float mL = mi * LOG2E;
    float p[4][4];
    float rs = 0.f;
    #pragma unroll
    for (int j = 0; j < 4; ++j)
      #pragma unroll
      for (int r = 0; r < 4; ++r){
        p[j][r] = exp2f(fmaf(sv[j][r], LOG2E, -mL));
        rs += p[j][r];
      }
    rs += __shfl_xor(rs, 16);
    rs += __shfl_xor(rs, 32);
    li += rs;
    // stage P -> Ps[w][qrow=rq][key] (swizzled), 4x ds_write_b64
    #pragma unroll
    for (int j = 0; j < 4; ++j){
      u32x2 u;
      u[0] = pack_bf16x2(p[j][0], p[j][1]);
      u[1] = pack_bf16x2(p[j][2], p[j][3]);
      const int logical = rq*128 + j*32 + g*8;
      const int phys = logical ^ ((rq & 7) << 4);
      *(u32x2*)((char*)&Ps[w][0] + phys) = u;
    }
    asm volatile("s_waitcnt lgkmcnt(0)" ::: "memory");
    __builtin_amdgcn_sched_barrier(0);
    // PV: A = P (rows qrow), B = V^T (cols d)
    __builtin_amdgcn_s_setprio(1);
    #pragma unroll
    for (int kk = 0; kk < 2; ++kk){
      const int physp = (rq*128 + kk*64 + g*16) ^ ((rq & 7) << 4);
      bf16x8 pf = *(const bf16x8*)((const char*)&Ps[w][0] + physp);
      #pragma unroll
      for (int jd = 0; jd < 4; ++jd){
        const int drow = jd*16 + rq;
        const int physv = (drow*128 + kk*64 + g*16) ^ ((rq & 7) << 4);
        bf16x8 vf = *(const bf16x8*)((const char*)&Vts[cur][0] + physv);
        ao[jd] = MFMA16(pf, vf, ao[jd]);
      }
    }
    __builtin_amdgcn_s_setprio(0);
    if (kt + 1 < NT) writeV(cur ^ 1, vn);
    __syncthreads();
    #pragma unroll
    for (int j = 0; j < 4; ++j) dv[j] = dvn[j];
    cur ^= 1;
  }

  // output rows q0 + g*4 + r, cols jd*16 + rq
  ushort_t* ob = attnb + (size_t)b * S_ * E_ + h * D_;
  float inv[4];
  #pragma unroll
  for (int r = 0; r < 4; ++r){
    const int li_i = __builtin_amdgcn_ds_bpermute((g*4 + r) << 2,
                       __builtin_bit_cast(int, li));
    inv[r] = 1.f / __builtin_bit_cast(float, li_i);
  }
  #pragma unroll
  for (int jd = 0; jd < 4; ++jd)
    #pragma unroll
    for (int r = 0; r < 4; ++r){
      const int qrow = q0 + g*4 + r;
      ob[(size_t)qrow * E_ + jd*16 + rq] = f2bf(ao[jd][r] * inv[r]);
    }
}

// ---------------- LayerNorm ----------------

template<int WB>
__global__ __launch_bounds__(256)
void ln_kernel(const float* __restrict__ in, const float* __restrict__ gam,
               const float* __restrict__ bet, float* __restrict__ outf,
               ushort_t* __restrict__ outb)
{
  const int lane = threadIdx.x & 63;
  const size_t row = (size_t)blockIdx.x * 4 + (threadIdx.x >> 6);
  const float* xr = in + row * E_;
  const int e0 = lane * 8;
  float4 a = *(const float4*)(xr + e0);
  float4 c = *(const float4*)(xr + e0 + 4);
  float y[8] = {a.x,a.y,a.z,a.w,c.x,c.y,c.z,c.w};
  float s = 0.f, s2 = 0.f;
  #pragma unroll
  for (int i = 0; i < 8; ++i){ s += y[i]; s2 += y[i]*y[i]; }
  #pragma unroll
  for (int m = 1; m < 64; m <<= 1){ s += __shfl_xor(s, m); s2 += __shfl_xor(s2, m); }
  const float mu = s * (1.f / E_);
  const float rsd = rsqrtf(s2 * (1.f / E_) - mu*mu + 1e-5f);
  float4 G0 = *(const float4*)(gam + e0), G1 = *(const float4*)(gam + e0 + 4);
  float4 B0 = *(const float4*)(bet + e0), B1 = *(const float4*)(bet + e0 + 4);
  float gg[8] = {G0.x,G0.y,G0.z,G0.w,G1.x,G1.y,G1.z,G1.w};
  float bb[8] = {B0.x,B0.y,B0.z,B0.w,B1.x,B1.y,B1.z,B1.w};
  float o[8];
  #pragma unroll
  for (int i = 0; i < 8; ++i) o[i] = (y[i] - mu) * rsd * gg[i] + bb[i];
  float4 w0 = {o[0],o[1],o[2],o[3]}, w1 = {o[4],o[5],o[6],o[7]};
  *(float4*)(outf + row * E_ + e0) = w0;
  *(float4*)(outf + row * E_ + e0 + 4) = w1;
  if (WB){
    u16x8 ob;
    #pragma unroll
    for (int i = 0; i < 8; ++i) ob[i] = f2bf(o[i]);
    *(u16x8*)(outb + row * E_ + e0) = ob;
  }
}

// ---------------- launch ----------------

extern "C" void kernel_launch(void* const* d_in, const int* in_sizes, int n_in,
                              void* d_out, int out_size, void* d_ws, size_t ws_size,
                              hipStream_t stream)
{
  const float* x    = (const float*)d_in[0];
  const float* dist = (const float*)d_in[1];
  const int*   mask = (const int*)d_in[2];
  const float* Wq = (const float*)d_in[3];  const float* bq = (const float*)d_in[4];
  const float* Wk = (const float*)d_in[5];  const float* bk = (const float*)d_in[6];
  const float* Wv = (const float*)d_in[7];  const float* bv = (const float*)d_in[8];
  const float* Wo = (const float*)d_in[9];  const float* bo = (const float*)d_in[10];
  const float* W1 = (const float*)d_in[11]; const float* b1 = (const float*)d_in[12];
  const float* W2 = (const float*)d_in[13]; const float* b2 = (const float*)d_in[14];
  const float* g1 = (const float*)d_in[15]; const float* be1 = (const float*)d_in[16];
  const float* g2 = (const float*)d_in[17]; const float* be2 = (const float*)d_in[18];
  float* out = (float*)d_out;

  char* ws = (char*)d_ws;
  ushort_t* xb    = (ushort_t*)(ws + 0);          // 8,388,608
  ushort_t* wtqkv = (ushort_t*)(ws + 8388608);    // 1,572,864
  ushort_t* wto   = (ushort_t*)(ws + 9961472);    //   524,288
  ushort_t* wt1   = (ushort_t*)(ws + 10485760);   // 2,097,152
  ushort_t* wt2   = (ushort_t*)(ws + 12582912);   // 2,097,152
  float*    bqkv  = (float*)(ws + 14680064);      //     6,144
  ushort_t* qkvb  = (ushort_t*)(ws + 14686208);   // 25,165,824
  ushort_t* attnb = (ushort_t*)(ws + 39852032);   //  8,388,608
  ushort_t* f1    = (ushort_t*)(ws + 14686208);   // 33,554,432 (aliases qkvb+attnb, dead by then)
  // distb aliases resid1+hf (both first written AFTER attention completes)
  ushort_t* distb = (ushort_t*)(ws + 48240640);   // 33,554,432
  float*    resid1= (float*)(ws + 48240640);      // 16,777,216
  float*    resid2= (float*)(ws + 48240640);      // aliases resid1 (dead by then)
  float*    hf    = (float*)(ws + 65017856);      // 16,777,216
  ushort_t* hb    = (ushort_t*)(ws + 81795072);   //  8,388,608  (total 90,183,680)

  k_cast_x<<<2048, 256, 0, stream>>>(x, xb);
  prep_dist<<<8192, 256, 0, stream>>>(dist, mask, distb);
  k_transpose<<<16*16, 256, 0, stream>>>(Wq, wtqkv + 0,      512, 512);
  k_transpose<<<16*16, 256, 0, stream>>>(Wk, wtqkv + 262144, 512, 512);
  k_transpose<<<16*16, 256, 0, stream>>>(Wv, wtqkv + 524288, 512, 512);
  k_transpose<<<16*16, 256, 0, stream>>>(Wo, wto, 512, 512);
  k_transpose<<<16*64, 256, 0, stream>>>(W1, wt1, 512, 2048);
  k_transpose<<<64*16, 256, 0, stream>>>(W2, wt2, 2048, 512);
  k_bias3<<<6, 256, 0, stream>>>(bq, bk, bv, bqkv);

  gemm_bt<0><<<64*12, 256, 0, stream>>>(xb, wtqkv, bqkv, nullptr, qkvb, M_, 1536, 512);
  attn_fused<<<1024, 256, 0, stream>>>(qkvb, distb, attnb);
  gemm_bt<1><<<64*4, 256, 0, stream>>>(attnb, wto, bo, x, resid1, M_, 512, 512);
  ln_kernel<1><<<2048, 256, 0, stream>>>(resid1, g1, be1, hf, hb);
  gemm_bt<2><<<64*16, 256, 0, stream>>>(hb, wt1, b1, nullptr, f1, M_, 2048, 512);
  gemm_bt<1><<<64*4, 256, 0, stream>>>(f1, wt2, b2, hf, resid2, M_, 512, 2048);
  ln_kernel<0><<<2048, 256, 0, stream>>>(resid2, g2, be2, out, nullptr);
}